// Round 6
// baseline (260.993 us; speedup 1.0000x reference)
//
#include <hip/hip_runtime.h>
#include <hip/hip_fp16.h>

#define NB 64
#define NS 512
#define NH 1024
#define NITERS 10

// -log(512)
#define LOG_INV_NS (-6.238324625039508f)

using half8 = _Float16 __attribute__((ext_vector_type(8)));
using half4 = _Float16 __attribute__((ext_vector_type(4)));
using f32x4 = float __attribute__((ext_vector_type(4)));

// ---------------------------------------------------------------------------
// Kernel 1: cast x/y to raw f16 (streaming, store depends only on load) and
// compute per-row inv L2 norms as a side product. Normalization itself is
// deferred to the GEMM epilogue so stores never wait on the reduce chain.
__global__ __launch_bounds__(256) void prep_kernel(
    const float* __restrict__ x, const float* __restrict__ y,
    _Float16* __restrict__ xh, _Float16* __restrict__ yh,
    float* __restrict__ inv_nx, float* __restrict__ inv_ny) {
  int wid = threadIdx.x >> 6, lane = threadIdx.x & 63;
  int row0 = blockIdx.x * 8 + wid * 2;  // even; pair never straddles x/y
  bool isx = row0 < NB * NS;
  int lrow = isx ? row0 : row0 - NB * NS;
  const float* src = (isx ? x : y) + (size_t)lrow * NH;
  _Float16* dst = (isx ? xh : yh) + (size_t)lrow * NH;
  float* invp = (isx ? inv_nx : inv_ny) + lrow;

  float s0 = 0.f, s1 = 0.f;
#pragma unroll
  for (int j = 0; j < 4; ++j) {
    float4 v0 = ((const float4*)src)[j * 64 + lane];
    float4 v1 = ((const float4*)src)[256 + j * 64 + lane];
    // stores issue immediately (no dependency on the reduce)
    half4 h0 = {(_Float16)v0.x, (_Float16)v0.y, (_Float16)v0.z, (_Float16)v0.w};
    half4 h1 = {(_Float16)v1.x, (_Float16)v1.y, (_Float16)v1.z, (_Float16)v1.w};
    ((half4*)dst)[j * 64 + lane] = h0;
    ((half4*)(dst + NH))[j * 64 + lane] = h1;
    s0 += v0.x * v0.x + v0.y * v0.y + v0.z * v0.z + v0.w * v0.w;
    s1 += v1.x * v1.x + v1.y * v1.y + v1.z * v1.z + v1.w * v1.w;
  }
#pragma unroll
  for (int o = 32; o; o >>= 1) {
    s0 += __shfl_xor(s0, o, 64);
    s1 += __shfl_xor(s1, o, 64);
  }
  if (lane == 0) {
    invp[0] = 1.0f / fmaxf(sqrtf(s0), 1e-12f);
    invp[1] = 1.0f / fmaxf(sqrtf(s1), 1e-12f);
  }
}

// fp32-fallback: norms only (used with the fallback GEMM when ws is small)
__global__ __launch_bounds__(256) void norms_kernel(
    const float* __restrict__ x, const float* __restrict__ y,
    float* __restrict__ inv_nx, float* __restrict__ inv_ny) {
  int wid = threadIdx.x >> 6, lane = threadIdx.x & 63;
  int row = blockIdx.x * 4 + wid;
  bool isx = row < NB * NS;
  int lrow = isx ? row : row - NB * NS;
  const float* src = (isx ? x : y) + (size_t)lrow * NH;
  float s = 0.f;
#pragma unroll
  for (int j = 0; j < 4; ++j) {
    float4 v = ((const float4*)src)[j * 64 + lane];
    s += v.x * v.x + v.y * v.y + v.z * v.z + v.w * v.w;
  }
#pragma unroll
  for (int o = 32; o; o >>= 1) s += __shfl_xor(s, o, 64);
  if (lane == 0) {
    float inv = 1.0f / fmaxf(sqrtf(s), 1e-12f);
    if (isx) inv_nx[lrow] = inv; else inv_ny[lrow] = inv;
  }
}

// ---------------------------------------------------------------------------
// Kernel 2 (f16 path): batched GEMM on RAW f16 inputs; cosine normalization
// applied in the epilogue: S = acc * inv_nx[m] * inv_ny[n].
// 128x128 tile, 4 waves (64x64 each), 16x16x32 f16 MFMA, BK=64,
// 2-phase register prefetch, LDS-transpose epilogue for coalesced f16 stores.
__global__ __launch_bounds__(256) void gemm_f16(
    const _Float16* __restrict__ xh, const _Float16* __restrict__ yh,
    const float* __restrict__ inv_nx, const float* __restrict__ inv_ny,
    _Float16* __restrict__ Sh) {
  __shared__ __align__(16) char smem[2][128 * 72 * 2];
  __shared__ float invAs[128], invBs[128];
  _Float16(*As)[72] = (_Float16(*)[72])smem[0];
  _Float16(*Bs)[72] = (_Float16(*)[72])smem[1];

  int blk = blockIdx.x;
  int bs = blk & 7, rest = blk >> 3;
  int tile = rest & 15, bq = rest >> 4;
  int b = bq * 8 + bs;
  int tm = (tile >> 2) * 128, tn = (tile & 3) * 128;
  int tid = threadIdx.x;
  int wid = tid >> 6, lane = tid & 63;
  int wr = (wid >> 1) * 64, wc = (wid & 1) * 64;
  int fr = lane & 15, fq = lane >> 4;

  if (tid < 128) invAs[tid] = inv_nx[b * NS + tm + tid];
  else invBs[tid - 128] = inv_ny[b * NS + tn + (tid - 128)];

  // staging: rows r0=tid>>2 and r1=64+r0, col chunk kc=(tid&3)*16 (16 halves).
  int r0 = tid >> 2, kc = (tid & 3) * 16;
  int r1 = 64 + r0;
  const _Float16* xb = xh + ((size_t)b * NS + tm) * NH + kc;
  const _Float16* yb = yh + ((size_t)b * NS + tn) * NH + kc;

  f32x4 acc[4][4] = {};
  half8 ra[4], rb[4];

#define GLOAD(K0)                                                  \
  do {                                                             \
    ra[0] = *(const half8*)(xb + (size_t)r0 * NH + (K0) + 0);      \
    ra[1] = *(const half8*)(xb + (size_t)r0 * NH + (K0) + 8);      \
    ra[2] = *(const half8*)(xb + (size_t)r1 * NH + (K0) + 0);      \
    ra[3] = *(const half8*)(xb + (size_t)r1 * NH + (K0) + 8);      \
    rb[0] = *(const half8*)(yb + (size_t)r0 * NH + (K0) + 0);      \
    rb[1] = *(const half8*)(yb + (size_t)r0 * NH + (K0) + 8);      \
    rb[2] = *(const half8*)(yb + (size_t)r1 * NH + (K0) + 0);      \
    rb[3] = *(const half8*)(yb + (size_t)r1 * NH + (K0) + 8);      \
  } while (0)

  GLOAD(0);

  for (int k0 = 0; k0 < NH; k0 += 64) {
    __syncthreads();
    *(half8*)&As[r0][kc + 0] = ra[0];
    *(half8*)&As[r0][kc + 8] = ra[1];
    *(half8*)&As[r1][kc + 0] = ra[2];
    *(half8*)&As[r1][kc + 8] = ra[3];
    *(half8*)&Bs[r0][kc + 0] = rb[0];
    *(half8*)&Bs[r0][kc + 8] = rb[1];
    *(half8*)&Bs[r1][kc + 0] = rb[2];
    *(half8*)&Bs[r1][kc + 8] = rb[3];
    __syncthreads();
    if (k0 + 64 < NH) GLOAD(k0 + 64);
#pragma unroll
    for (int ks = 0; ks < 2; ++ks) {
      half8 af[4], bf[4];
#pragma unroll
      for (int i = 0; i < 4; ++i) {
        af[i] = *(const half8*)&As[wr + 16 * i + fr][ks * 32 + 8 * fq];
        bf[i] = *(const half8*)&Bs[wc + 16 * i + fr][ks * 32 + 8 * fq];
      }
#pragma unroll
      for (int i = 0; i < 4; ++i)
#pragma unroll
        for (int j = 0; j < 4; ++j)
          acc[i][j] = __builtin_amdgcn_mfma_f32_16x16x32_f16(af[i], bf[j], acc[i][j], 0, 0, 0);
    }
  }
#undef GLOAD

  // Epilogue: scale by inv norms, stage C tile f16 in LDS, coalesced stores.
  // C/D layout: col = lane&15 (n), row = (lane>>4)*4 + reg (m).
  _Float16(*Cs)[132] = (_Float16(*)[132])smem[0];
  __syncthreads();
#pragma unroll
  for (int i = 0; i < 4; ++i)
#pragma unroll
    for (int j = 0; j < 4; ++j) {
      int rr = wr + 16 * i + 4 * fq;
      int cc = wc + 16 * j + fr;
      float ib = invBs[cc];
#pragma unroll
      for (int p = 0; p < 4; ++p)
        Cs[rr + p][cc] = (_Float16)(acc[i][j][p] * invAs[rr + p] * ib);
    }
  __syncthreads();
  {
    _Float16* Sb = Sh + (size_t)b * NS * NS;
    int row = tid >> 1, h0 = (tid & 1) * 64;
    _Float16* gout = Sb + (size_t)(tm + row) * NS + tn + h0;
#pragma unroll
    for (int c = 0; c < 8; ++c)
      *(half8*)(gout + c * 8) = *(const half8*)&Cs[row][h0 + c * 8];
  }
}

// ---------------------------------------------------------------------------
// Kernel 2b (fallback, fp32 inputs): normalization during staging, BK=32.
__global__ __launch_bounds__(256) void gemm_f32(
    const float* __restrict__ x, const float* __restrict__ y,
    const float* __restrict__ inv_nx, const float* __restrict__ inv_ny,
    _Float16* __restrict__ Sh) {
  __shared__ _Float16 As[128][40];
  __shared__ _Float16 Bs[128][40];

  int blk = blockIdx.x;
  int bs = blk & 7, rest = blk >> 3;
  int tile = rest & 15, bq = rest >> 4;
  int b = bq * 8 + bs;
  int tm = (tile >> 2) * 128, tn = (tile & 3) * 128;
  int tid = threadIdx.x;
  int wid = tid >> 6, lane = tid & 63;
  int wr = (wid >> 1) * 64, wc = (wid & 1) * 64;
  int fr = lane & 15, fq = lane >> 4;

  int srow = tid >> 1;
  int skh = (tid & 1) * 16;
  const float* xb32 = x + ((size_t)b * NS + tm + srow) * NH + skh;
  const float* yb32 = y + ((size_t)b * NS + tn + srow) * NH + skh;
  float ax = inv_nx[b * NS + tm + srow];
  float ay = inv_ny[b * NS + tn + srow];

  f32x4 acc[4][4] = {};

  for (int k0 = 0; k0 < NH; k0 += 32) {
    __syncthreads();
    {
      const float4* px = (const float4*)(xb32 + k0);
      const float4* py = (const float4*)(yb32 + k0);
      alignas(16) _Float16 ta[16];
      alignas(16) _Float16 tb[16];
#pragma unroll
      for (int j = 0; j < 4; ++j) {
        float4 v = px[j];
        ta[4 * j + 0] = (_Float16)(v.x * ax);
        ta[4 * j + 1] = (_Float16)(v.y * ax);
        ta[4 * j + 2] = (_Float16)(v.z * ax);
        ta[4 * j + 3] = (_Float16)(v.w * ax);
      }
#pragma unroll
      for (int j = 0; j < 4; ++j) {
        float4 v = py[j];
        tb[4 * j + 0] = (_Float16)(v.x * ay);
        tb[4 * j + 1] = (_Float16)(v.y * ay);
        tb[4 * j + 2] = (_Float16)(v.z * ay);
        tb[4 * j + 3] = (_Float16)(v.w * ay);
      }
      *(half8*)&As[srow][skh + 0] = *(half8*)&ta[0];
      *(half8*)&As[srow][skh + 8] = *(half8*)&ta[8];
      *(half8*)&Bs[srow][skh + 0] = *(half8*)&tb[0];
      *(half8*)&Bs[srow][skh + 8] = *(half8*)&tb[8];
    }
    __syncthreads();

    half8 af[4], bf[4];
#pragma unroll
    for (int i = 0; i < 4; ++i) {
      af[i] = *(const half8*)&As[wr + 16 * i + fr][8 * fq];
      bf[i] = *(const half8*)&Bs[wc + 16 * i + fr][8 * fq];
    }
#pragma unroll
    for (int i = 0; i < 4; ++i)
#pragma unroll
      for (int j = 0; j < 4; ++j)
        acc[i][j] = __builtin_amdgcn_mfma_f32_16x16x32_f16(af[i], bf[j], acc[i][j], 0, 0, 0);
  }

  _Float16* Sb = Sh + (size_t)b * NS * NS;
#pragma unroll
  for (int i = 0; i < 4; ++i)
#pragma unroll
    for (int j = 0; j < 4; ++j) {
      int rr = tm + wr + 16 * i + 4 * fq;
      int cc = tn + wc + 16 * j + fr;
#pragma unroll
      for (int p = 0; p < 4; ++p)
        Sb[(size_t)(rr + p) * NS + cc] = (_Float16)acc[i][j][p];
    }
}

// ---------------------------------------------------------------------------
// Kernel 3: init V=0, W=log_nu
__global__ __launch_bounds__(256) void init_kernel(float* __restrict__ V, float* __restrict__ W) {
  int i = blockIdx.x * 256 + threadIdx.x;  // 32768
  V[i] = 0.f;
  W[i] = LOG_INV_NS;
}

// ---------------------------------------------------------------------------
// Kernel 4 (u/row step): U[b][m] = log_mu - log( sum_n exp(f*S[b][m][n] + W[b][n]) )
__global__ __launch_bounds__(256) void u_kernel(
    const _Float16* __restrict__ Sh, const float* __restrict__ W,
    float* __restrict__ U, float f) {
  __shared__ float Wt[8][65];
  int blk = blockIdx.x;
  int bs = blk & 7, rest = blk >> 3;
  int rowgrp = rest & 31, bq = rest >> 5;
  int b = bq * 8 + bs;
  int t = threadIdx.x;
#pragma unroll
  for (int i = 0; i < 2; ++i) {
    int idx = t + 256 * i;
    Wt[idx & 7][idx >> 3] = W[b * NS + idx];
  }
  __syncthreads();
  int w = t >> 6, l = t & 63;
  float wn[8];
#pragma unroll
  for (int e = 0; e < 8; ++e) wn[e] = Wt[e][l];
  int m0 = rowgrp * 16 + w * 4;
  const _Float16* Sb = Sh + ((size_t)b * NS + m0) * NS + 8 * l;
  float sum[4] = {0.f, 0.f, 0.f, 0.f};
#pragma unroll
  for (int k = 0; k < 4; ++k) {
    half8 hv = *(const half8*)(Sb + (size_t)k * NS);
#pragma unroll
    for (int e = 0; e < 8; ++e) sum[k] += __expf(fmaf(f, (float)hv[e], wn[e]));
  }
#pragma unroll
  for (int o = 32; o; o >>= 1) {
#pragma unroll
    for (int k = 0; k < 4; ++k) sum[k] += __shfl_xor(sum[k], o, 64);
  }
  if (l == 0) {
#pragma unroll
    for (int k = 0; k < 4; ++k)
      U[b * NS + m0 + k] = LOG_INV_NS - __logf(sum[k]);
  }
}

// ---------------------------------------------------------------------------
// Kernel 5 (v/col step)
__global__ __launch_bounds__(256) void v_kernel(
    const _Float16* __restrict__ Sh, const float* __restrict__ U,
    float* __restrict__ V, float* __restrict__ W,
    float f, int last, float* __restrict__ outPart) {
  __shared__ float Ul[NS];
  __shared__ float partC[16][128];
  __shared__ float partD[16][128];
  __shared__ float red[128];
  int blk = blockIdx.x;
  int bs = blk & 7, rest = blk >> 3;
  int q = rest & 3, bq = rest >> 2;
  int b = bq * 8 + bs;
  int t = threadIdx.x;
  Ul[t] = U[b * NS + t];
  Ul[t + 256] = U[b * NS + t + 256];
  __syncthreads();

  int r = t >> 4, cg = t & 15;
  const _Float16* Sb = Sh + (size_t)b * NS * NS + q * 128 + cg * 8;
  float c[8] = {}, d[8] = {};
  if (!last) {
#pragma unroll 4
    for (int s = 0; s < 32; ++s) {
      int m = s * 16 + r;
      half8 hv = *(const half8*)(Sb + (size_t)m * NS);
      float um = Ul[m];
#pragma unroll
      for (int e = 0; e < 8; ++e) c[e] += __expf(fmaf(f, (float)hv[e], um));
    }
  } else {
#pragma unroll 2
    for (int s = 0; s < 32; ++s) {
      int m = s * 16 + r;
      half8 hv = *(const half8*)(Sb + (size_t)m * NS);
      float um = Ul[m];
#pragma unroll
      for (int e = 0; e < 8; ++e) {
        float sv = (float)hv[e];
        float ev = __expf(fmaf(f, sv, um));
        c[e] += ev;
        d[e] = fmaf(sv, ev, d[e]);
      }
    }
  }
  *(f32x4*)&partC[r][cg * 8 + 0] = f32x4{c[0], c[1], c[2], c[3]};
  *(f32x4*)&partC[r][cg * 8 + 4] = f32x4{c[4], c[5], c[6], c[7]};
  if (last) {
    *(f32x4*)&partD[r][cg * 8 + 0] = f32x4{d[0], d[1], d[2], d[3]};
    *(f32x4*)&partD[r][cg * 8 + 4] = f32x4{d[4], d[5], d[6], d[7]};
  }
  __syncthreads();
  if (t < 128) {
    float ct = 0.f;
#pragma unroll
    for (int r2 = 0; r2 < 16; ++r2) ct += partC[r2][t];
    float vnew = LOG_INV_NS - __logf(ct);
    int n = b * NS + q * 128 + t;
    float vold = V[n];
    V[n] = vnew;
    W[n] = 2.f * vnew - vold;
    if (last) {
      float dt = 0.f;
#pragma unroll
      for (int r2 = 0; r2 < 16; ++r2) dt += partD[r2][t];
      red[t] = dt / ct;
    }
  }
  if (last) {
    __syncthreads();
    for (int s2 = 64; s2 > 0; s2 >>= 1) {
      if (t < s2) red[t] += red[t + s2];
      __syncthreads();
    }
    if (t == 0) outPart[b * 4 + q] = red[0] * (1.0f / (float)NS);
  }
}

// ---------------------------------------------------------------------------
// Kernel 6: combine 4 partials per batch (deterministic)
__global__ void combine_kernel(const float* __restrict__ outPart, float* __restrict__ out) {
  int b = threadIdx.x;  // 64 threads
  out[b] = outPart[4 * b] + outPart[4 * b + 1] + outPart[4 * b + 2] + outPart[4 * b + 3];
}

// ---------------------------------------------------------------------------
extern "C" void kernel_launch(void* const* d_in, const int* in_sizes, int n_in,
                              void* d_out, int out_size, void* d_ws, size_t ws_size,
                              hipStream_t stream) {
  (void)in_sizes; (void)n_in; (void)out_size;
  const float* x = (const float*)d_in[0];
  const float* y = (const float*)d_in[1];
  float* out = (float*)d_out;

  char* ws = (char*)d_ws;
  _Float16* Sh = (_Float16*)ws;                                // 32 MiB
  float* fregion = (float*)(ws + (size_t)NB * NS * NS * 2);
  float* inv_nx = fregion;                                     // 32768
  float* inv_ny = inv_nx + NB * NS;
  float* U = inv_ny + NB * NS;
  float* V = U + NB * NS;
  float* W = V + NB * NS;
  float* outPart = W + NB * NS;                                // 256
  size_t base = (size_t)NB * NS * NS * 2 + (5 * NB * NS + 256) * 4;
  _Float16* xh = (_Float16*)(ws + base);
  _Float16* yh = xh + (size_t)NB * NS * NH;
  size_t need = base + (size_t)2 * NB * NS * NH * 2;           // ~160.6 MiB
  bool f16in = ws_size >= need;

  if (f16in) {
    prep_kernel<<<(2 * NB * NS) / 8, 256, 0, stream>>>(x, y, xh, yh, inv_nx, inv_ny);
    gemm_f16<<<1024, 256, 0, stream>>>(xh, yh, inv_nx, inv_ny, Sh);
  } else {
    norms_kernel<<<(2 * NB * NS) / 4, 256, 0, stream>>>(x, y, inv_nx, inv_ny);
    gemm_f32<<<1024, 256, 0, stream>>>(x, y, inv_nx, inv_ny, Sh);
  }
  init_kernel<<<(NB * NS) / 256, 256, 0, stream>>>(V, W);

  for (int t = 1; t <= NITERS; ++t) {
    float f = 10.0f * (float)t;
    u_kernel<<<2048, 256, 0, stream>>>(Sh, W, U, f);
    v_kernel<<<256, 256, 0, stream>>>(Sh, U, V, W, f, t == NITERS ? 1 : 0, outPart);
  }
  combine_kernel<<<1, 64, 0, stream>>>(outPart, out);
}

// Round 7
// 258.579 us; speedup vs baseline: 1.0093x; 1.0093x over previous
//
#include <hip/hip_runtime.h>
#include <hip/hip_fp16.h>

#define NB 64
#define NS 512
#define NH 1024
#define NITERS 10

// -log(512)
#define LOG_INV_NS (-6.238324625039508f)

using half8 = _Float16 __attribute__((ext_vector_type(8)));
using half4 = _Float16 __attribute__((ext_vector_type(4)));
using f32x4 = float __attribute__((ext_vector_type(4)));

// ---------------------------------------------------------------------------
// Kernel 1: cast x/y to raw f16 + per-row inv L2 norms.
// One row per wave; each lane owns 16 CONTIGUOUS floats -> two 16B half8
// stores per lane (full 64B lines per store instruction).
__global__ __launch_bounds__(256) void prep_kernel(
    const float* __restrict__ x, const float* __restrict__ y,
    _Float16* __restrict__ xh, _Float16* __restrict__ yh,
    float* __restrict__ inv_nx, float* __restrict__ inv_ny) {
  int wid = threadIdx.x >> 6, lane = threadIdx.x & 63;
  int row = blockIdx.x * 4 + wid;  // 0..65535
  bool isx = row < NB * NS;
  int lrow = isx ? row : row - NB * NS;
  const float* src = (isx ? x : y) + (size_t)lrow * NH;
  _Float16* dst = (isx ? xh : yh) + (size_t)lrow * NH;

  const float4* p = (const float4*)src + 4 * lane;
  float4 a0 = p[0], a1 = p[1], a2 = p[2], a3 = p[3];

  half8 h0 = {(_Float16)a0.x, (_Float16)a0.y, (_Float16)a0.z, (_Float16)a0.w,
              (_Float16)a1.x, (_Float16)a1.y, (_Float16)a1.z, (_Float16)a1.w};
  half8 h1 = {(_Float16)a2.x, (_Float16)a2.y, (_Float16)a2.z, (_Float16)a2.w,
              (_Float16)a3.x, (_Float16)a3.y, (_Float16)a3.z, (_Float16)a3.w};
  ((half8*)dst)[2 * lane + 0] = h0;
  ((half8*)dst)[2 * lane + 1] = h1;

  float s = a0.x * a0.x + a0.y * a0.y + a0.z * a0.z + a0.w * a0.w;
  s += a1.x * a1.x + a1.y * a1.y + a1.z * a1.z + a1.w * a1.w;
  s += a2.x * a2.x + a2.y * a2.y + a2.z * a2.z + a2.w * a2.w;
  s += a3.x * a3.x + a3.y * a3.y + a3.z * a3.z + a3.w * a3.w;
#pragma unroll
  for (int o = 32; o; o >>= 1) s += __shfl_xor(s, o, 64);
  if (lane == 0) {
    float inv = 1.0f / fmaxf(sqrtf(s), 1e-12f);
    (isx ? inv_nx : inv_ny)[lrow] = inv;
  }
}

// fp32-fallback: norms only (used with the fallback GEMM when ws is small)
__global__ __launch_bounds__(256) void norms_kernel(
    const float* __restrict__ x, const float* __restrict__ y,
    float* __restrict__ inv_nx, float* __restrict__ inv_ny) {
  int wid = threadIdx.x >> 6, lane = threadIdx.x & 63;
  int row = blockIdx.x * 4 + wid;
  bool isx = row < NB * NS;
  int lrow = isx ? row : row - NB * NS;
  const float* src = (isx ? x : y) + (size_t)lrow * NH;
  float s = 0.f;
#pragma unroll
  for (int j = 0; j < 4; ++j) {
    float4 v = ((const float4*)src)[j * 64 + lane];
    s += v.x * v.x + v.y * v.y + v.z * v.z + v.w * v.w;
  }
#pragma unroll
  for (int o = 32; o; o >>= 1) s += __shfl_xor(s, o, 64);
  if (lane == 0) {
    float inv = 1.0f / fmaxf(sqrtf(s), 1e-12f);
    if (isx) inv_nx[lrow] = inv; else inv_ny[lrow] = inv;
  }
}

// ---------------------------------------------------------------------------
// Kernel 2 (f16 path): batched GEMM on RAW f16 inputs; cosine normalization
// applied in the epilogue: S = acc * inv_nx[m] * inv_ny[n].
// 128x128 tile, 4 waves (64x64 each), 16x16x32 f16 MFMA, BK=64,
// 2-phase register prefetch, LDS-transpose epilogue for coalesced f16 stores.
__global__ __launch_bounds__(256) void gemm_f16(
    const _Float16* __restrict__ xh, const _Float16* __restrict__ yh,
    const float* __restrict__ inv_nx, const float* __restrict__ inv_ny,
    _Float16* __restrict__ Sh) {
  __shared__ __align__(16) char smem[2][128 * 72 * 2];
  __shared__ float invAs[128], invBs[128];
  _Float16(*As)[72] = (_Float16(*)[72])smem[0];
  _Float16(*Bs)[72] = (_Float16(*)[72])smem[1];

  int blk = blockIdx.x;
  int bs = blk & 7, rest = blk >> 3;
  int tile = rest & 15, bq = rest >> 4;
  int b = bq * 8 + bs;
  int tm = (tile >> 2) * 128, tn = (tile & 3) * 128;
  int tid = threadIdx.x;
  int wid = tid >> 6, lane = tid & 63;
  int wr = (wid >> 1) * 64, wc = (wid & 1) * 64;
  int fr = lane & 15, fq = lane >> 4;

  if (tid < 128) invAs[tid] = inv_nx[b * NS + tm + tid];
  else invBs[tid - 128] = inv_ny[b * NS + tn + (tid - 128)];

  // staging: rows r0=tid>>2 and r1=64+r0, col chunk kc=(tid&3)*16 (16 halves).
  int r0 = tid >> 2, kc = (tid & 3) * 16;
  int r1 = 64 + r0;
  const _Float16* xb = xh + ((size_t)b * NS + tm) * NH + kc;
  const _Float16* yb = yh + ((size_t)b * NS + tn) * NH + kc;

  f32x4 acc[4][4] = {};
  half8 ra[4], rb[4];

#define GLOAD(K0)                                                  \
  do {                                                             \
    ra[0] = *(const half8*)(xb + (size_t)r0 * NH + (K0) + 0);      \
    ra[1] = *(const half8*)(xb + (size_t)r0 * NH + (K0) + 8);      \
    ra[2] = *(const half8*)(xb + (size_t)r1 * NH + (K0) + 0);      \
    ra[3] = *(const half8*)(xb + (size_t)r1 * NH + (K0) + 8);      \
    rb[0] = *(const half8*)(yb + (size_t)r0 * NH + (K0) + 0);      \
    rb[1] = *(const half8*)(yb + (size_t)r0 * NH + (K0) + 8);      \
    rb[2] = *(const half8*)(yb + (size_t)r1 * NH + (K0) + 0);      \
    rb[3] = *(const half8*)(yb + (size_t)r1 * NH + (K0) + 8);      \
  } while (0)

  GLOAD(0);

  for (int k0 = 0; k0 < NH; k0 += 64) {
    __syncthreads();
    *(half8*)&As[r0][kc + 0] = ra[0];
    *(half8*)&As[r0][kc + 8] = ra[1];
    *(half8*)&As[r1][kc + 0] = ra[2];
    *(half8*)&As[r1][kc + 8] = ra[3];
    *(half8*)&Bs[r0][kc + 0] = rb[0];
    *(half8*)&Bs[r0][kc + 8] = rb[1];
    *(half8*)&Bs[r1][kc + 0] = rb[2];
    *(half8*)&Bs[r1][kc + 8] = rb[3];
    __syncthreads();
    if (k0 + 64 < NH) GLOAD(k0 + 64);
#pragma unroll
    for (int ks = 0; ks < 2; ++ks) {
      half8 af[4], bf[4];
#pragma unroll
      for (int i = 0; i < 4; ++i) {
        af[i] = *(const half8*)&As[wr + 16 * i + fr][ks * 32 + 8 * fq];
        bf[i] = *(const half8*)&Bs[wc + 16 * i + fr][ks * 32 + 8 * fq];
      }
#pragma unroll
      for (int i = 0; i < 4; ++i)
#pragma unroll
        for (int j = 0; j < 4; ++j)
          acc[i][j] = __builtin_amdgcn_mfma_f32_16x16x32_f16(af[i], bf[j], acc[i][j], 0, 0, 0);
    }
  }
#undef GLOAD

  // Epilogue: scale by inv norms, stage C tile f16 in LDS, coalesced stores.
  // C/D layout: col = lane&15 (n), row = (lane>>4)*4 + reg (m).
  _Float16(*Cs)[132] = (_Float16(*)[132])smem[0];
  __syncthreads();
#pragma unroll
  for (int i = 0; i < 4; ++i)
#pragma unroll
    for (int j = 0; j < 4; ++j) {
      int rr = wr + 16 * i + 4 * fq;
      int cc = wc + 16 * j + fr;
      float ib = invBs[cc];
#pragma unroll
      for (int p = 0; p < 4; ++p)
        Cs[rr + p][cc] = (_Float16)(acc[i][j][p] * invAs[rr + p] * ib);
    }
  __syncthreads();
  {
    _Float16* Sb = Sh + (size_t)b * NS * NS;
    int row = tid >> 1, h0 = (tid & 1) * 64;
    _Float16* gout = Sb + (size_t)(tm + row) * NS + tn + h0;
#pragma unroll
    for (int c = 0; c < 8; ++c)
      *(half8*)(gout + c * 8) = *(const half8*)&Cs[row][h0 + c * 8];
  }
}

// ---------------------------------------------------------------------------
// Kernel 2b (fallback, fp32 inputs): normalization during staging, BK=32.
__global__ __launch_bounds__(256) void gemm_f32(
    const float* __restrict__ x, const float* __restrict__ y,
    const float* __restrict__ inv_nx, const float* __restrict__ inv_ny,
    _Float16* __restrict__ Sh) {
  __shared__ _Float16 As[128][40];
  __shared__ _Float16 Bs[128][40];

  int blk = blockIdx.x;
  int bs = blk & 7, rest = blk >> 3;
  int tile = rest & 15, bq = rest >> 4;
  int b = bq * 8 + bs;
  int tm = (tile >> 2) * 128, tn = (tile & 3) * 128;
  int tid = threadIdx.x;
  int wid = tid >> 6, lane = tid & 63;
  int wr = (wid >> 1) * 64, wc = (wid & 1) * 64;
  int fr = lane & 15, fq = lane >> 4;

  int srow = tid >> 1;
  int skh = (tid & 1) * 16;
  const float* xb32 = x + ((size_t)b * NS + tm + srow) * NH + skh;
  const float* yb32 = y + ((size_t)b * NS + tn + srow) * NH + skh;
  float ax = inv_nx[b * NS + tm + srow];
  float ay = inv_ny[b * NS + tn + srow];

  f32x4 acc[4][4] = {};

  for (int k0 = 0; k0 < NH; k0 += 32) {
    __syncthreads();
    {
      const float4* px = (const float4*)(xb32 + k0);
      const float4* py = (const float4*)(yb32 + k0);
      alignas(16) _Float16 ta[16];
      alignas(16) _Float16 tb[16];
#pragma unroll
      for (int j = 0; j < 4; ++j) {
        float4 v = px[j];
        ta[4 * j + 0] = (_Float16)(v.x * ax);
        ta[4 * j + 1] = (_Float16)(v.y * ax);
        ta[4 * j + 2] = (_Float16)(v.z * ax);
        ta[4 * j + 3] = (_Float16)(v.w * ax);
      }
#pragma unroll
      for (int j = 0; j < 4; ++j) {
        float4 v = py[j];
        tb[4 * j + 0] = (_Float16)(v.x * ay);
        tb[4 * j + 1] = (_Float16)(v.y * ay);
        tb[4 * j + 2] = (_Float16)(v.z * ay);
        tb[4 * j + 3] = (_Float16)(v.w * ay);
      }
      *(half8*)&As[srow][skh + 0] = *(half8*)&ta[0];
      *(half8*)&As[srow][skh + 8] = *(half8*)&ta[8];
      *(half8*)&Bs[srow][skh + 0] = *(half8*)&tb[0];
      *(half8*)&Bs[srow][skh + 8] = *(half8*)&tb[8];
    }
    __syncthreads();

    half8 af[4], bf[4];
#pragma unroll
    for (int i = 0; i < 4; ++i) {
      af[i] = *(const half8*)&As[wr + 16 * i + fr][8 * fq];
      bf[i] = *(const half8*)&Bs[wc + 16 * i + fr][8 * fq];
    }
#pragma unroll
    for (int i = 0; i < 4; ++i)
#pragma unroll
      for (int j = 0; j < 4; ++j)
        acc[i][j] = __builtin_amdgcn_mfma_f32_16x16x32_f16(af[i], bf[j], acc[i][j], 0, 0, 0);
  }

  _Float16* Sb = Sh + (size_t)b * NS * NS;
#pragma unroll
  for (int i = 0; i < 4; ++i)
#pragma unroll
    for (int j = 0; j < 4; ++j) {
      int rr = tm + wr + 16 * i + 4 * fq;
      int cc = tn + wc + 16 * j + fr;
#pragma unroll
      for (int p = 0; p < 4; ++p)
        Sb[(size_t)(rr + p) * NS + cc] = (_Float16)acc[i][j][p];
    }
}

// ---------------------------------------------------------------------------
// Kernel 3: init V=0, W=log_nu
__global__ __launch_bounds__(256) void init_kernel(float* __restrict__ V, float* __restrict__ W) {
  int i = blockIdx.x * 256 + threadIdx.x;  // 32768
  V[i] = 0.f;
  W[i] = LOG_INV_NS;
}

// ---------------------------------------------------------------------------
// Kernel 4 (u/row step): U[b][m] = log_mu - log( sum_n exp(f*S[b][m][n] + W[b][n]) )
__global__ __launch_bounds__(256) void u_kernel(
    const _Float16* __restrict__ Sh, const float* __restrict__ W,
    float* __restrict__ U, float f) {
  __shared__ float Wt[8][65];
  int blk = blockIdx.x;
  int bs = blk & 7, rest = blk >> 3;
  int rowgrp = rest & 31, bq = rest >> 5;
  int b = bq * 8 + bs;
  int t = threadIdx.x;
#pragma unroll
  for (int i = 0; i < 2; ++i) {
    int idx = t + 256 * i;
    Wt[idx & 7][idx >> 3] = W[b * NS + idx];
  }
  __syncthreads();
  int w = t >> 6, l = t & 63;
  float wn[8];
#pragma unroll
  for (int e = 0; e < 8; ++e) wn[e] = Wt[e][l];
  int m0 = rowgrp * 16 + w * 4;
  const _Float16* Sb = Sh + ((size_t)b * NS + m0) * NS + 8 * l;
  float sum[4] = {0.f, 0.f, 0.f, 0.f};
#pragma unroll
  for (int k = 0; k < 4; ++k) {
    half8 hv = *(const half8*)(Sb + (size_t)k * NS);
#pragma unroll
    for (int e = 0; e < 8; ++e) sum[k] += __expf(fmaf(f, (float)hv[e], wn[e]));
  }
#pragma unroll
  for (int o = 32; o; o >>= 1) {
#pragma unroll
    for (int k = 0; k < 4; ++k) sum[k] += __shfl_xor(sum[k], o, 64);
  }
  if (l == 0) {
#pragma unroll
    for (int k = 0; k < 4; ++k)
      U[b * NS + m0 + k] = LOG_INV_NS - __logf(sum[k]);
  }
}

// ---------------------------------------------------------------------------
// Kernel 5 (v/col step)
__global__ __launch_bounds__(256) void v_kernel(
    const _Float16* __restrict__ Sh, const float* __restrict__ U,
    float* __restrict__ V, float* __restrict__ W,
    float f, int last, float* __restrict__ outPart) {
  __shared__ float Ul[NS];
  __shared__ float partC[16][128];
  __shared__ float partD[16][128];
  __shared__ float red[128];
  int blk = blockIdx.x;
  int bs = blk & 7, rest = blk >> 3;
  int q = rest & 3, bq = rest >> 2;
  int b = bq * 8 + bs;
  int t = threadIdx.x;
  Ul[t] = U[b * NS + t];
  Ul[t + 256] = U[b * NS + t + 256];
  __syncthreads();

  int r = t >> 4, cg = t & 15;
  const _Float16* Sb = Sh + (size_t)b * NS * NS + q * 128 + cg * 8;
  float c[8] = {}, d[8] = {};
  if (!last) {
#pragma unroll 4
    for (int s = 0; s < 32; ++s) {
      int m = s * 16 + r;
      half8 hv = *(const half8*)(Sb + (size_t)m * NS);
      float um = Ul[m];
#pragma unroll
      for (int e = 0; e < 8; ++e) c[e] += __expf(fmaf(f, (float)hv[e], um));
    }
  } else {
#pragma unroll 2
    for (int s = 0; s < 32; ++s) {
      int m = s * 16 + r;
      half8 hv = *(const half8*)(Sb + (size_t)m * NS);
      float um = Ul[m];
#pragma unroll
      for (int e = 0; e < 8; ++e) {
        float sv = (float)hv[e];
        float ev = __expf(fmaf(f, sv, um));
        c[e] += ev;
        d[e] = fmaf(sv, ev, d[e]);
      }
    }
  }
  *(f32x4*)&partC[r][cg * 8 + 0] = f32x4{c[0], c[1], c[2], c[3]};
  *(f32x4*)&partC[r][cg * 8 + 4] = f32x4{c[4], c[5], c[6], c[7]};
  if (last) {
    *(f32x4*)&partD[r][cg * 8 + 0] = f32x4{d[0], d[1], d[2], d[3]};
    *(f32x4*)&partD[r][cg * 8 + 4] = f32x4{d[4], d[5], d[6], d[7]};
  }
  __syncthreads();
  if (t < 128) {
    float ct = 0.f;
#pragma unroll
    for (int r2 = 0; r2 < 16; ++r2) ct += partC[r2][t];
    float vnew = LOG_INV_NS - __logf(ct);
    int n = b * NS + q * 128 + t;
    float vold = V[n];
    V[n] = vnew;
    W[n] = 2.f * vnew - vold;
    if (last) {
      float dt = 0.f;
#pragma unroll
      for (int r2 = 0; r2 < 16; ++r2) dt += partD[r2][t];
      red[t] = dt / ct;
    }
  }
  if (last) {
    __syncthreads();
    for (int s2 = 64; s2 > 0; s2 >>= 1) {
      if (t < s2) red[t] += red[t + s2];
      __syncthreads();
    }
    if (t == 0) outPart[b * 4 + q] = red[0] * (1.0f / (float)NS);
  }
}

// ---------------------------------------------------------------------------
// Kernel 6: combine 4 partials per batch (deterministic)
__global__ void combine_kernel(const float* __restrict__ outPart, float* __restrict__ out) {
  int b = threadIdx.x;  // 64 threads
  out[b] = outPart[4 * b] + outPart[4 * b + 1] + outPart[4 * b + 2] + outPart[4 * b + 3];
}

// ---------------------------------------------------------------------------
extern "C" void kernel_launch(void* const* d_in, const int* in_sizes, int n_in,
                              void* d_out, int out_size, void* d_ws, size_t ws_size,
                              hipStream_t stream) {
  (void)in_sizes; (void)n_in; (void)out_size;
  const float* x = (const float*)d_in[0];
  const float* y = (const float*)d_in[1];
  float* out = (float*)d_out;

  char* ws = (char*)d_ws;
  _Float16* Sh = (_Float16*)ws;                                // 32 MiB
  float* fregion = (float*)(ws + (size_t)NB * NS * NS * 2);
  float* inv_nx = fregion;                                     // 32768
  float* inv_ny = inv_nx + NB * NS;
  float* U = inv_ny + NB * NS;
  float* V = U + NB * NS;
  float* W = V + NB * NS;
  float* outPart = W + NB * NS;                                // 256
  size_t base = (size_t)NB * NS * NS * 2 + (5 * NB * NS + 256) * 4;
  _Float16* xh = (_Float16*)(ws + base);
  _Float16* yh = xh + (size_t)NB * NS * NH;
  size_t need = base + (size_t)2 * NB * NS * NH * 2;           // ~160.6 MiB
  bool f16in = ws_size >= need;

  if (f16in) {
    prep_kernel<<<(2 * NB * NS) / 4, 256, 0, stream>>>(x, y, xh, yh, inv_nx, inv_ny);
    gemm_f16<<<1024, 256, 0, stream>>>(xh, yh, inv_nx, inv_ny, Sh);
  } else {
    norms_kernel<<<(2 * NB * NS) / 4, 256, 0, stream>>>(x, y, inv_nx, inv_ny);
    gemm_f32<<<1024, 256, 0, stream>>>(x, y, inv_nx, inv_ny, Sh);
  }
  init_kernel<<<(NB * NS) / 256, 256, 0, stream>>>(V, W);

  for (int t = 1; t <= NITERS; ++t) {
    float f = 10.0f * (float)t;
    u_kernel<<<2048, 256, 0, stream>>>(Sh, W, U, f);
    v_kernel<<<256, 256, 0, stream>>>(Sh, U, V, W, f, t == NITERS ? 1 : 0, outPart);
  }
  combine_kernel<<<1, 64, 0, stream>>>(outPart, out);
}

// Round 8
// 247.599 us; speedup vs baseline: 1.0541x; 1.0443x over previous
//
#include <hip/hip_runtime.h>
#include <hip/hip_fp16.h>

#define NB 64
#define NS 512
#define NH 1024
#define NITERS 10

// -log(512)
#define LOG_INV_NS (-6.238324625039508f)

using half8 = _Float16 __attribute__((ext_vector_type(8)));
using f32x4 = float __attribute__((ext_vector_type(4)));

// ---------------------------------------------------------------------------
// Fused kernel: batched cosine-score GEMM straight from fp32 inputs.
//   S[b][m][n] = (x[b][m]·y[b][n]) / (||x[b][m]|| ||y[b][n]||),  f16 out.
// 128x128 tile, 4 waves (64x64), 16x16x32 f16 MFMA, BK=32, register prefetch.
// Row norms computed IN-KERNEL during staging (each block streams full K for
// its rows): per-thread partial sum-of-squares + shfl pair reduce.
// Epilogue: scale acc * invA[m] * invB[n], LDS transpose, coalesced stores.
__global__ __launch_bounds__(256) void gemm_fused(
    const float* __restrict__ x, const float* __restrict__ y,
    _Float16* __restrict__ Sh) {
  __shared__ __align__(16) char smem[128 * 132 * 2];  // staging + C overlay
  _Float16(*As)[40] = (_Float16(*)[40])smem;                    // 10240 B
  _Float16(*Bs)[40] = (_Float16(*)[40])(smem + 10240);          // 10240 B
  __shared__ float invA[128], invB[128];

  int blk = blockIdx.x;
  int bs = blk & 7, rest = blk >> 3;          // XCD pinning: batch%8 fixed/XCD
  int tile = rest & 15, bq = rest >> 4;
  int b = bq * 8 + bs;
  int tm = (tile >> 2) * 128, tn = (tile & 3) * 128;
  int tid = threadIdx.x;
  int wid = tid >> 6, lane = tid & 63;
  int wr = (wid >> 1) * 64, wc = (wid & 1) * 64;
  int fr = lane & 15, fq = lane >> 4;

  // staging: row srow (0..127), k-half skh in {0,16}; two threads per row.
  int srow = tid >> 1;
  int skh = (tid & 1) * 16;
  const float* xb = x + ((size_t)b * NS + tm + srow) * NH + skh;
  const float* yb = y + ((size_t)b * NS + tn + srow) * NH + skh;

  f32x4 acc[4][4] = {};
  float4 rx[4], ry[4];
  float sqx = 0.f, sqy = 0.f;

#define GLOAD(K0)                                        \
  do {                                                   \
    const float4* px = (const float4*)(xb + (K0));       \
    const float4* py = (const float4*)(yb + (K0));       \
    rx[0] = px[0]; rx[1] = px[1]; rx[2] = px[2]; rx[3] = px[3]; \
    ry[0] = py[0]; ry[1] = py[1]; ry[2] = py[2]; ry[3] = py[3]; \
  } while (0)

  GLOAD(0);

  for (int k0 = 0; k0 < NH; k0 += 32) {
    __syncthreads();
    {
      alignas(16) _Float16 ta[16];
      alignas(16) _Float16 tb[16];
#pragma unroll
      for (int j = 0; j < 4; ++j) {
        float4 v = rx[j];
        ta[4 * j + 0] = (_Float16)v.x;
        ta[4 * j + 1] = (_Float16)v.y;
        ta[4 * j + 2] = (_Float16)v.z;
        ta[4 * j + 3] = (_Float16)v.w;
        sqx += v.x * v.x + v.y * v.y + v.z * v.z + v.w * v.w;
      }
#pragma unroll
      for (int j = 0; j < 4; ++j) {
        float4 v = ry[j];
        tb[4 * j + 0] = (_Float16)v.x;
        tb[4 * j + 1] = (_Float16)v.y;
        tb[4 * j + 2] = (_Float16)v.z;
        tb[4 * j + 3] = (_Float16)v.w;
        sqy += v.x * v.x + v.y * v.y + v.z * v.z + v.w * v.w;
      }
      *(half8*)&As[srow][skh + 0] = *(half8*)&ta[0];
      *(half8*)&As[srow][skh + 8] = *(half8*)&ta[8];
      *(half8*)&Bs[srow][skh + 0] = *(half8*)&tb[0];
      *(half8*)&Bs[srow][skh + 8] = *(half8*)&tb[8];
    }
    __syncthreads();
    if (k0 + 32 < NH) GLOAD(k0 + 32);

    half8 af[4], bf[4];
#pragma unroll
    for (int i = 0; i < 4; ++i) {
      af[i] = *(const half8*)&As[wr + 16 * i + fr][8 * fq];
      bf[i] = *(const half8*)&Bs[wc + 16 * i + fr][8 * fq];
    }
#pragma unroll
    for (int i = 0; i < 4; ++i)
#pragma unroll
      for (int j = 0; j < 4; ++j)
        acc[i][j] = __builtin_amdgcn_mfma_f32_16x16x32_f16(af[i], bf[j], acc[i][j], 0, 0, 0);
  }
#undef GLOAD

  // finalize row norms: two partials per row sit in adjacent lanes (tid, tid^1)
  sqx += __shfl_xor(sqx, 1, 64);
  sqy += __shfl_xor(sqy, 1, 64);
  if ((tid & 1) == 0) {
    invA[srow] = 1.0f / fmaxf(sqrtf(sqx), 1e-12f);
    invB[srow] = 1.0f / fmaxf(sqrtf(sqy), 1e-12f);
  }

  // Epilogue: scale by inv norms, stage C tile f16 in LDS, coalesced stores.
  // C/D layout: col = lane&15 (n), row = (lane>>4)*4 + reg (m).
  _Float16(*Cs)[132] = (_Float16(*)[132])smem;
  __syncthreads();   // invA/invB visible; staging LDS reads all done
#pragma unroll
  for (int i = 0; i < 4; ++i)
#pragma unroll
    for (int j = 0; j < 4; ++j) {
      int rr = wr + 16 * i + 4 * fq;
      int cc = wc + 16 * j + fr;
      float ib = invB[cc];
#pragma unroll
      for (int p = 0; p < 4; ++p)
        Cs[rr + p][cc] = (_Float16)(acc[i][j][p] * invA[rr + p] * ib);
    }
  __syncthreads();
  {
    _Float16* Sb = Sh + (size_t)b * NS * NS;
    int row = tid >> 1, h0 = (tid & 1) * 64;
    _Float16* gout = Sb + (size_t)(tm + row) * NS + tn + h0;
#pragma unroll
    for (int c = 0; c < 8; ++c)
      *(half8*)(gout + c * 8) = *(const half8*)&Cs[row][h0 + c * 8];
  }
}

// ---------------------------------------------------------------------------
// Kernel 3: init V=0, W=log_nu
__global__ __launch_bounds__(256) void init_kernel(float* __restrict__ V, float* __restrict__ W) {
  int i = blockIdx.x * 256 + threadIdx.x;  // 32768
  V[i] = 0.f;
  W[i] = LOG_INV_NS;
}

// ---------------------------------------------------------------------------
// Kernel 4 (u/row step): U[b][m] = log_mu - log( sum_n exp(f*S[b][m][n] + W[b][n]) )
__global__ __launch_bounds__(256) void u_kernel(
    const _Float16* __restrict__ Sh, const float* __restrict__ W,
    float* __restrict__ U, float f) {
  __shared__ float Wt[8][65];
  int blk = blockIdx.x;
  int bs = blk & 7, rest = blk >> 3;
  int rowgrp = rest & 31, bq = rest >> 5;
  int b = bq * 8 + bs;
  int t = threadIdx.x;
#pragma unroll
  for (int i = 0; i < 2; ++i) {
    int idx = t + 256 * i;
    Wt[idx & 7][idx >> 3] = W[b * NS + idx];
  }
  __syncthreads();
  int w = t >> 6, l = t & 63;
  float wn[8];
#pragma unroll
  for (int e = 0; e < 8; ++e) wn[e] = Wt[e][l];
  int m0 = rowgrp * 16 + w * 4;
  const _Float16* Sb = Sh + ((size_t)b * NS + m0) * NS + 8 * l;
  float sum[4] = {0.f, 0.f, 0.f, 0.f};
#pragma unroll
  for (int k = 0; k < 4; ++k) {
    half8 hv = *(const half8*)(Sb + (size_t)k * NS);
#pragma unroll
    for (int e = 0; e < 8; ++e) sum[k] += __expf(fmaf(f, (float)hv[e], wn[e]));
  }
#pragma unroll
  for (int o = 32; o; o >>= 1) {
#pragma unroll
    for (int k = 0; k < 4; ++k) sum[k] += __shfl_xor(sum[k], o, 64);
  }
  if (l == 0) {
#pragma unroll
    for (int k = 0; k < 4; ++k)
      U[b * NS + m0 + k] = LOG_INV_NS - __logf(sum[k]);
  }
}

// ---------------------------------------------------------------------------
// Kernel 5 (v/col step)
__global__ __launch_bounds__(256) void v_kernel(
    const _Float16* __restrict__ Sh, const float* __restrict__ U,
    float* __restrict__ V, float* __restrict__ W,
    float f, int last, float* __restrict__ outPart) {
  __shared__ float Ul[NS];
  __shared__ float partC[16][128];
  __shared__ float partD[16][128];
  __shared__ float red[128];
  int blk = blockIdx.x;
  int bs = blk & 7, rest = blk >> 3;
  int q = rest & 3, bq = rest >> 2;
  int b = bq * 8 + bs;
  int t = threadIdx.x;
  Ul[t] = U[b * NS + t];
  Ul[t + 256] = U[b * NS + t + 256];
  __syncthreads();

  int r = t >> 4, cg = t & 15;
  const _Float16* Sb = Sh + (size_t)b * NS * NS + q * 128 + cg * 8;
  float c[8] = {}, d[8] = {};
  if (!last) {
#pragma unroll 4
    for (int s = 0; s < 32; ++s) {
      int m = s * 16 + r;
      half8 hv = *(const half8*)(Sb + (size_t)m * NS);
      float um = Ul[m];
#pragma unroll
      for (int e = 0; e < 8; ++e) c[e] += __expf(fmaf(f, (float)hv[e], um));
    }
  } else {
#pragma unroll 2
    for (int s = 0; s < 32; ++s) {
      int m = s * 16 + r;
      half8 hv = *(const half8*)(Sb + (size_t)m * NS);
      float um = Ul[m];
#pragma unroll
      for (int e = 0; e < 8; ++e) {
        float sv = (float)hv[e];
        float ev = __expf(fmaf(f, sv, um));
        c[e] += ev;
        d[e] = fmaf(sv, ev, d[e]);
      }
    }
  }
  *(f32x4*)&partC[r][cg * 8 + 0] = f32x4{c[0], c[1], c[2], c[3]};
  *(f32x4*)&partC[r][cg * 8 + 4] = f32x4{c[4], c[5], c[6], c[7]};
  if (last) {
    *(f32x4*)&partD[r][cg * 8 + 0] = f32x4{d[0], d[1], d[2], d[3]};
    *(f32x4*)&partD[r][cg * 8 + 4] = f32x4{d[4], d[5], d[6], d[7]};
  }
  __syncthreads();
  if (t < 128) {
    float ct = 0.f;
#pragma unroll
    for (int r2 = 0; r2 < 16; ++r2) ct += partC[r2][t];
    float vnew = LOG_INV_NS - __logf(ct);
    int n = b * NS + q * 128 + t;
    float vold = V[n];
    V[n] = vnew;
    W[n] = 2.f * vnew - vold;
    if (last) {
      float dt = 0.f;
#pragma unroll
      for (int r2 = 0; r2 < 16; ++r2) dt += partD[r2][t];
      red[t] = dt / ct;
    }
  }
  if (last) {
    __syncthreads();
    for (int s2 = 64; s2 > 0; s2 >>= 1) {
      if (t < s2) red[t] += red[t + s2];
      __syncthreads();
    }
    if (t == 0) outPart[b * 4 + q] = red[0] * (1.0f / (float)NS);
  }
}

// ---------------------------------------------------------------------------
// Kernel 6: combine 4 partials per batch (deterministic)
__global__ void combine_kernel(const float* __restrict__ outPart, float* __restrict__ out) {
  int b = threadIdx.x;  // 64 threads
  out[b] = outPart[4 * b] + outPart[4 * b + 1] + outPart[4 * b + 2] + outPart[4 * b + 3];
}

// ---------------------------------------------------------------------------
extern "C" void kernel_launch(void* const* d_in, const int* in_sizes, int n_in,
                              void* d_out, int out_size, void* d_ws, size_t ws_size,
                              hipStream_t stream) {
  (void)in_sizes; (void)n_in; (void)out_size; (void)ws_size;
  const float* x = (const float*)d_in[0];
  const float* y = (const float*)d_in[1];
  float* out = (float*)d_out;

  char* ws = (char*)d_ws;
  _Float16* Sh = (_Float16*)ws;                                // 32 MiB
  float* fregion = (float*)(ws + (size_t)NB * NS * NS * 2);
  float* U = fregion;                                          // 32768
  float* V = U + NB * NS;
  float* W = V + NB * NS;
  float* outPart = W + NB * NS;                                // 256

  gemm_fused<<<1024, 256, 0, stream>>>(x, y, Sh);
  init_kernel<<<(NB * NS) / 256, 256, 0, stream>>>(V, W);

  for (int t = 1; t <= NITERS; ++t) {
    float f = 10.0f * (float)t;
    u_kernel<<<2048, 256, 0, stream>>>(Sh, W, U, f);
    v_kernel<<<256, 256, 0, stream>>>(Sh, U, V, W, f, t == NITERS ? 1 : 0, outPart);
  }
  combine_kernel<<<1, 64, 0, stream>>>(outPart, out);
}

// Round 9
// 225.776 us; speedup vs baseline: 1.1560x; 1.0967x over previous
//
#include <hip/hip_runtime.h>
#include <hip/hip_fp16.h>

#define NB 64
#define NS 512
#define NH 1024
#define NITERS 10

// -log(512)
#define LOG_INV_NS (-6.238324625039508f)

using half8 = _Float16 __attribute__((ext_vector_type(8)));
using f32x4 = float __attribute__((ext_vector_type(4)));

// ---------------------------------------------------------------------------
// Fused kernel: batched cosine-score GEMM straight from fp32 inputs.
//   S[b][m][n] = (x[b][m].y[b][n]) / (||x[b][m]|| ||y[b][n]||), f16 out.
// 256x256 tile (4 blocks/batch -> each input row staged by only 2 blocks),
// 512 threads / 8 waves (2Mx4N, wave = 128x64 = 8x4 frags), BK=32,
// register prefetch, in-kernel row norms, epilogue normalization.
// Block decode keeps all 4 tiles of a batch on one XCD (blk%8 == batch%8).
__global__ __launch_bounds__(512) void gemm_fused(
    const float* __restrict__ x, const float* __restrict__ y,
    _Float16* __restrict__ Sh) {
  __shared__ _Float16 As[256][40];   // 20480 B, 80B row stride (verified layout)
  __shared__ _Float16 Bs[256][40];   // 20480 B
  __shared__ float invA[256], invB[256];

  int blk = blockIdx.x;
  int b = blk & 63;                  // batch; blk%8 = b%8 -> XCD pinned
  int tile = blk >> 6;               // 0..3
  int tm = (tile >> 1) * 256, tn = (tile & 1) * 256;
  int tid = threadIdx.x;
  int wid = tid >> 6, lane = tid & 63;
  int wr = (wid >> 2) * 128;         // {0,128}
  int wc = (wid & 3) * 64;           // {0,64,128,192}
  int fr = lane & 15, fq = lane >> 4;

  // staging: row srow (0..255), k-half skh in {0,16}; two threads per row.
  int srow = tid >> 1;
  int skh = (tid & 1) * 16;
  const float* xb = x + ((size_t)b * NS + tm + srow) * NH + skh;
  const float* yb = y + ((size_t)b * NS + tn + srow) * NH + skh;

  f32x4 acc[8][4] = {};
  float4 rx[4], ry[4];
  float sqx = 0.f, sqy = 0.f;

#define GLOAD(K0)                                                     \
  do {                                                                \
    const float4* px = (const float4*)(xb + (K0));                    \
    const float4* py = (const float4*)(yb + (K0));                    \
    rx[0] = px[0]; rx[1] = px[1]; rx[2] = px[2]; rx[3] = px[3];       \
    ry[0] = py[0]; ry[1] = py[1]; ry[2] = py[2]; ry[3] = py[3];       \
  } while (0)

  GLOAD(0);

  for (int k0 = 0; k0 < NH; k0 += 32) {
    __syncthreads();
    {
      alignas(16) _Float16 ta[16];
      alignas(16) _Float16 tb[16];
#pragma unroll
      for (int j = 0; j < 4; ++j) {
        float4 v = rx[j];
        ta[4 * j + 0] = (_Float16)v.x;
        ta[4 * j + 1] = (_Float16)v.y;
        ta[4 * j + 2] = (_Float16)v.z;
        ta[4 * j + 3] = (_Float16)v.w;
        sqx += v.x * v.x + v.y * v.y + v.z * v.z + v.w * v.w;
      }
#pragma unroll
      for (int j = 0; j < 4; ++j) {
        float4 v = ry[j];
        tb[4 * j + 0] = (_Float16)v.x;
        tb[4 * j + 1] = (_Float16)v.y;
        tb[4 * j + 2] = (_Float16)v.z;
        tb[4 * j + 3] = (_Float16)v.w;
        sqy += v.x * v.x + v.y * v.y + v.z * v.z + v.w * v.w;
      }
      *(half8*)&As[srow][skh + 0] = *(half8*)&ta[0];
      *(half8*)&As[srow][skh + 8] = *(half8*)&ta[8];
      *(half8*)&Bs[srow][skh + 0] = *(half8*)&tb[0];
      *(half8*)&Bs[srow][skh + 8] = *(half8*)&tb[8];
    }
    __syncthreads();
    if (k0 + 32 < NH) GLOAD(k0 + 32);

    half8 af[8], bf[4];
#pragma unroll
    for (int i = 0; i < 8; ++i)
      af[i] = *(const half8*)&As[wr + 16 * i + fr][8 * fq];
#pragma unroll
    for (int j = 0; j < 4; ++j)
      bf[j] = *(const half8*)&Bs[wc + 16 * j + fr][8 * fq];
#pragma unroll
    for (int i = 0; i < 8; ++i)
#pragma unroll
      for (int j = 0; j < 4; ++j)
        acc[i][j] = __builtin_amdgcn_mfma_f32_16x16x32_f16(af[i], bf[j], acc[i][j], 0, 0, 0);
  }
#undef GLOAD

  // finalize row norms: two partials per row in adjacent lanes (tid, tid^1)
  sqx += __shfl_xor(sqx, 1, 64);
  sqy += __shfl_xor(sqy, 1, 64);
  if ((tid & 1) == 0) {
    invA[srow] = 1.0f / fmaxf(sqrtf(sqx), 1e-12f);
    invB[srow] = 1.0f / fmaxf(sqrtf(sqy), 1e-12f);
  }
  __syncthreads();  // invA/invB visible to all waves

  // Epilogue: S = acc * invA[m] * invB[n], direct f16 stores.
  // C/D layout: col = lane&15 (n), row = (lane>>4)*4 + reg (m).
  _Float16* Sb = Sh + (size_t)b * NS * NS;
#pragma unroll
  for (int i = 0; i < 8; ++i)
#pragma unroll
    for (int j = 0; j < 4; ++j) {
      int rr = wr + 16 * i + 4 * fq;
      int cc = wc + 16 * j + fr;
      float ib = invB[cc];
#pragma unroll
      for (int p = 0; p < 4; ++p)
        Sb[(size_t)(tm + rr + p) * NS + tn + cc] =
            (_Float16)(acc[i][j][p] * invA[rr + p] * ib);
    }
}

// ---------------------------------------------------------------------------
// Kernel 3: init V=0, W=log_nu
__global__ __launch_bounds__(256) void init_kernel(float* __restrict__ V, float* __restrict__ W) {
  int i = blockIdx.x * 256 + threadIdx.x;  // 32768
  V[i] = 0.f;
  W[i] = LOG_INV_NS;
}

// ---------------------------------------------------------------------------
// Kernel 4 (u/row step): U[b][m] = log_mu - log( sum_n exp(f*S[b][m][n] + W[b][n]) )
__global__ __launch_bounds__(256) void u_kernel(
    const _Float16* __restrict__ Sh, const float* __restrict__ W,
    float* __restrict__ U, float f) {
  __shared__ float Wt[8][65];
  int blk = blockIdx.x;
  int bs = blk & 7, rest = blk >> 3;
  int rowgrp = rest & 31, bq = rest >> 5;
  int b = bq * 8 + bs;
  int t = threadIdx.x;
#pragma unroll
  for (int i = 0; i < 2; ++i) {
    int idx = t + 256 * i;
    Wt[idx & 7][idx >> 3] = W[b * NS + idx];
  }
  __syncthreads();
  int w = t >> 6, l = t & 63;
  float wn[8];
#pragma unroll
  for (int e = 0; e < 8; ++e) wn[e] = Wt[e][l];
  int m0 = rowgrp * 16 + w * 4;
  const _Float16* Sb = Sh + ((size_t)b * NS + m0) * NS + 8 * l;
  float sum[4] = {0.f, 0.f, 0.f, 0.f};
#pragma unroll
  for (int k = 0; k < 4; ++k) {
    half8 hv = *(const half8*)(Sb + (size_t)k * NS);
#pragma unroll
    for (int e = 0; e < 8; ++e) sum[k] += __expf(fmaf(f, (float)hv[e], wn[e]));
  }
#pragma unroll
  for (int o = 32; o; o >>= 1) {
#pragma unroll
    for (int k = 0; k < 4; ++k) sum[k] += __shfl_xor(sum[k], o, 64);
  }
  if (l == 0) {
#pragma unroll
    for (int k = 0; k < 4; ++k)
      U[b * NS + m0 + k] = LOG_INV_NS - __logf(sum[k]);
  }
}

// ---------------------------------------------------------------------------
// Kernel 5 (v/col step)
__global__ __launch_bounds__(256) void v_kernel(
    const _Float16* __restrict__ Sh, const float* __restrict__ U,
    float* __restrict__ V, float* __restrict__ W,
    float f, int last, float* __restrict__ outPart) {
  __shared__ float Ul[NS];
  __shared__ float partC[16][128];
  __shared__ float partD[16][128];
  __shared__ float red[128];
  int blk = blockIdx.x;
  int bs = blk & 7, rest = blk >> 3;
  int q = rest & 3, bq = rest >> 2;
  int b = bq * 8 + bs;
  int t = threadIdx.x;
  Ul[t] = U[b * NS + t];
  Ul[t + 256] = U[b * NS + t + 256];
  __syncthreads();

  int r = t >> 4, cg = t & 15;
  const _Float16* Sb = Sh + (size_t)b * NS * NS + q * 128 + cg * 8;
  float c[8] = {}, d[8] = {};
  if (!last) {
#pragma unroll 4
    for (int s = 0; s < 32; ++s) {
      int m = s * 16 + r;
      half8 hv = *(const half8*)(Sb + (size_t)m * NS);
      float um = Ul[m];
#pragma unroll
      for (int e = 0; e < 8; ++e) c[e] += __expf(fmaf(f, (float)hv[e], um));
    }
  } else {
#pragma unroll 2
    for (int s = 0; s < 32; ++s) {
      int m = s * 16 + r;
      half8 hv = *(const half8*)(Sb + (size_t)m * NS);
      float um = Ul[m];
#pragma unroll
      for (int e = 0; e < 8; ++e) {
        float sv = (float)hv[e];
        float ev = __expf(fmaf(f, sv, um));
        c[e] += ev;
        d[e] = fmaf(sv, ev, d[e]);
      }
    }
  }
  *(f32x4*)&partC[r][cg * 8 + 0] = f32x4{c[0], c[1], c[2], c[3]};
  *(f32x4*)&partC[r][cg * 8 + 4] = f32x4{c[4], c[5], c[6], c[7]};
  if (last) {
    *(f32x4*)&partD[r][cg * 8 + 0] = f32x4{d[0], d[1], d[2], d[3]};
    *(f32x4*)&partD[r][cg * 8 + 4] = f32x4{d[4], d[5], d[6], d[7]};
  }
  __syncthreads();
  if (t < 128) {
    float ct = 0.f;
#pragma unroll
    for (int r2 = 0; r2 < 16; ++r2) ct += partC[r2][t];
    float vnew = LOG_INV_NS - __logf(ct);
    int n = b * NS + q * 128 + t;
    float vold = V[n];
    V[n] = vnew;
    W[n] = 2.f * vnew - vold;
    if (last) {
      float dt = 0.f;
#pragma unroll
      for (int r2 = 0; r2 < 16; ++r2) dt += partD[r2][t];
      red[t] = dt / ct;
    }
  }
  if (last) {
    __syncthreads();
    for (int s2 = 64; s2 > 0; s2 >>= 1) {
      if (t < s2) red[t] += red[t + s2];
      __syncthreads();
    }
    if (t == 0) outPart[b * 4 + q] = red[0] * (1.0f / (float)NS);
  }
}

// ---------------------------------------------------------------------------
// Kernel 6: combine 4 partials per batch (deterministic)
__global__ void combine_kernel(const float* __restrict__ outPart, float* __restrict__ out) {
  int b = threadIdx.x;  // 64 threads
  out[b] = outPart[4 * b] + outPart[4 * b + 1] + outPart[4 * b + 2] + outPart[4 * b + 3];
}

// ---------------------------------------------------------------------------
extern "C" void kernel_launch(void* const* d_in, const int* in_sizes, int n_in,
                              void* d_out, int out_size, void* d_ws, size_t ws_size,
                              hipStream_t stream) {
  (void)in_sizes; (void)n_in; (void)out_size; (void)ws_size;
  const float* x = (const float*)d_in[0];
  const float* y = (const float*)d_in[1];
  float* out = (float*)d_out;

  char* ws = (char*)d_ws;
  _Float16* Sh = (_Float16*)ws;                                // 32 MiB
  float* fregion = (float*)(ws + (size_t)NB * NS * NS * 2);
  float* U = fregion;                                          // 32768
  float* V = U + NB * NS;
  float* W = V + NB * NS;
  float* outPart = W + NB * NS;                                // 256

  gemm_fused<<<256, 512, 0, stream>>>(x, y, Sh);
  init_kernel<<<(NB * NS) / 256, 256, 0, stream>>>(V, W);

  for (int t = 1; t <= NITERS; ++t) {
    float f = 10.0f * (float)t;
    u_kernel<<<2048, 256, 0, stream>>>(Sh, W, U, f);
    v_kernel<<<256, 256, 0, stream>>>(Sh, U, V, W, f, t == NITERS ? 1 : 0, outPart);
  }
  combine_kernel<<<1, 64, 0, stream>>>(outPart, out);
}

// Round 10
// 222.185 us; speedup vs baseline: 1.1747x; 1.0162x over previous
//
#include <hip/hip_runtime.h>
#include <hip/hip_fp16.h>

#define NB 64
#define NS 512
#define NH 1024
#define NITERS 10

// -log(512)
#define LOG_INV_NS (-6.238324625039508f)

using half8 = _Float16 __attribute__((ext_vector_type(8)));
using f32x4 = float __attribute__((ext_vector_type(4)));

// ---------------------------------------------------------------------------
// Fused kernel: batched cosine-score GEMM straight from fp32 inputs.
//   S[b][m][n] = (x[b][m].y[b][n]) / (||x[b][m]|| ||y[b][n]||), f16 out.
// 256x256 tile, 512 threads / 8 waves (2Mx4N, wave = 128x64), BK=32.
// LDS DOUBLE-BUFFER: one barrier per K-step; staging (cast+ds_write) of tile
// k+1 overlaps MFMA of tile k within each wave; GLOAD(k+2) issued before the
// MFMA phase so L2 latency is covered by it.
// In-kernel row norms; epilogue normalization; XCD-pinned block decode.
__global__ __launch_bounds__(512) void gemm_fused(
    const float* __restrict__ x, const float* __restrict__ y,
    _Float16* __restrict__ Sh) {
  __shared__ _Float16 As[2][256][40];   // 2 x 20480 B
  __shared__ _Float16 Bs[2][256][40];   // 2 x 20480 B
  __shared__ float invA[256], invB[256];

  int blk = blockIdx.x;
  int b = blk & 63;                  // batch; blk%8 = b%8 -> XCD pinned
  int tile = blk >> 6;               // 0..3
  int tm = (tile >> 1) * 256, tn = (tile & 1) * 256;
  int tid = threadIdx.x;
  int wid = tid >> 6, lane = tid & 63;
  int wr = (wid >> 2) * 128;         // {0,128}
  int wc = (wid & 3) * 64;           // {0,64,128,192}
  int fr = lane & 15, fq = lane >> 4;

  // staging: row srow (0..255), k-half skh in {0,16}; two threads per row.
  int srow = tid >> 1;
  int skh = (tid & 1) * 16;
  const float* xb = x + ((size_t)b * NS + tm + srow) * NH + skh;
  const float* yb = y + ((size_t)b * NS + tn + srow) * NH + skh;

  f32x4 acc[8][4] = {};
  float4 rx[4], ry[4];
  float sqx = 0.f, sqy = 0.f;

#define GLOAD(K0)                                                     \
  do {                                                                \
    const float4* px = (const float4*)(xb + (K0));                    \
    const float4* py = (const float4*)(yb + (K0));                    \
    rx[0] = px[0]; rx[1] = px[1]; rx[2] = px[2]; rx[3] = px[3];       \
    ry[0] = py[0]; ry[1] = py[1]; ry[2] = py[2]; ry[3] = py[3];       \
  } while (0)

  // cast current rx/ry -> f16, accumulate sum-of-squares, write buffer BUF
#define CAST_WRITE(BUF)                                               \
  do {                                                                \
    alignas(16) _Float16 ta[16];                                      \
    alignas(16) _Float16 tb[16];                                      \
    _Pragma("unroll") for (int j = 0; j < 4; ++j) {                   \
      float4 v = rx[j];                                               \
      ta[4 * j + 0] = (_Float16)v.x;                                  \
      ta[4 * j + 1] = (_Float16)v.y;                                  \
      ta[4 * j + 2] = (_Float16)v.z;                                  \
      ta[4 * j + 3] = (_Float16)v.w;                                  \
      sqx += v.x * v.x + v.y * v.y + v.z * v.z + v.w * v.w;           \
    }                                                                 \
    _Pragma("unroll") for (int j = 0; j < 4; ++j) {                   \
      float4 v = ry[j];                                               \
      tb[4 * j + 0] = (_Float16)v.x;                                  \
      tb[4 * j + 1] = (_Float16)v.y;                                  \
      tb[4 * j + 2] = (_Float16)v.z;                                  \
      tb[4 * j + 3] = (_Float16)v.w;                                  \
      sqy += v.x * v.x + v.y * v.y + v.z * v.z + v.w * v.w;           \
    }                                                                 \
    *(half8*)&As[BUF][srow][skh + 0] = *(half8*)&ta[0];               \
    *(half8*)&As[BUF][srow][skh + 8] = *(half8*)&ta[8];               \
    *(half8*)&Bs[BUF][srow][skh + 0] = *(half8*)&tb[0];               \
    *(half8*)&Bs[BUF][srow][skh + 8] = *(half8*)&tb[8];               \
  } while (0)

  // prologue: stage chunk 0 into buf 0, prefetch chunk 1 into regs
  GLOAD(0);
  CAST_WRITE(0);
  GLOAD(32);

  for (int s = 0; s < 32; ++s) {
    __syncthreads();                 // buf[s&1] staged; buf[s&1^1] drained
    int cur = s & 1;
    if (s < 31) {
      CAST_WRITE(cur ^ 1);           // stage chunk s+1 (overlaps MFMA below)
      if (s < 30) GLOAD((s + 2) * 32);  // prefetch chunk s+2
    }
    half8 bf[4];
#pragma unroll
    for (int j = 0; j < 4; ++j)
      bf[j] = *(const half8*)&Bs[cur][wc + 16 * j + fr][8 * fq];
#pragma unroll
    for (int i = 0; i < 8; ++i) {
      half8 af = *(const half8*)&As[cur][wr + 16 * i + fr][8 * fq];
#pragma unroll
      for (int j = 0; j < 4; ++j)
        acc[i][j] = __builtin_amdgcn_mfma_f32_16x16x32_f16(af, bf[j], acc[i][j], 0, 0, 0);
    }
  }
#undef GLOAD
#undef CAST_WRITE

  // finalize row norms: two partials per row in adjacent lanes (tid, tid^1)
  sqx += __shfl_xor(sqx, 1, 64);
  sqy += __shfl_xor(sqy, 1, 64);
  if ((tid & 1) == 0) {
    invA[srow] = 1.0f / fmaxf(sqrtf(sqx), 1e-12f);
    invB[srow] = 1.0f / fmaxf(sqrtf(sqy), 1e-12f);
  }
  __syncthreads();  // invA/invB visible to all waves

  // Epilogue: S = acc * invA[m] * invB[n], direct f16 stores.
  // C/D layout: col = lane&15 (n), row = (lane>>4)*4 + reg (m).
  _Float16* Sb = Sh + (size_t)b * NS * NS;
#pragma unroll
  for (int i = 0; i < 8; ++i)
#pragma unroll
    for (int j = 0; j < 4; ++j) {
      int rr = wr + 16 * i + 4 * fq;
      int cc = wc + 16 * j + fr;
      float ib = invB[cc];
#pragma unroll
      for (int p = 0; p < 4; ++p)
        Sb[(size_t)(tm + rr + p) * NS + tn + cc] =
            (_Float16)(acc[i][j][p] * invA[rr + p] * ib);
    }
}

// ---------------------------------------------------------------------------
// Kernel 3: init V=0, W=log_nu
__global__ __launch_bounds__(256) void init_kernel(float* __restrict__ V, float* __restrict__ W) {
  int i = blockIdx.x * 256 + threadIdx.x;  // 32768
  V[i] = 0.f;
  W[i] = LOG_INV_NS;
}

// ---------------------------------------------------------------------------
// Kernel 4 (u/row step): U[b][m] = log_mu - log( sum_n exp(f*S[b][m][n] + W[b][n]) )
__global__ __launch_bounds__(256) void u_kernel(
    const _Float16* __restrict__ Sh, const float* __restrict__ W,
    float* __restrict__ U, float f) {
  __shared__ float Wt[8][65];
  int blk = blockIdx.x;
  int bs = blk & 7, rest = blk >> 3;
  int rowgrp = rest & 31, bq = rest >> 5;
  int b = bq * 8 + bs;
  int t = threadIdx.x;
#pragma unroll
  for (int i = 0; i < 2; ++i) {
    int idx = t + 256 * i;
    Wt[idx & 7][idx >> 3] = W[b * NS + idx];
  }
  __syncthreads();
  int w = t >> 6, l = t & 63;
  float wn[8];
#pragma unroll
  for (int e = 0; e < 8; ++e) wn[e] = Wt[e][l];
  int m0 = rowgrp * 16 + w * 4;
  const _Float16* Sb = Sh + ((size_t)b * NS + m0) * NS + 8 * l;
  float sum[4] = {0.f, 0.f, 0.f, 0.f};
#pragma unroll
  for (int k = 0; k < 4; ++k) {
    half8 hv = *(const half8*)(Sb + (size_t)k * NS);
#pragma unroll
    for (int e = 0; e < 8; ++e) sum[k] += __expf(fmaf(f, (float)hv[e], wn[e]));
  }
#pragma unroll
  for (int o = 32; o; o >>= 1) {
#pragma unroll
    for (int k = 0; k < 4; ++k) sum[k] += __shfl_xor(sum[k], o, 64);
  }
  if (l == 0) {
#pragma unroll
    for (int k = 0; k < 4; ++k)
      U[b * NS + m0 + k] = LOG_INV_NS - __logf(sum[k]);
  }
}

// ---------------------------------------------------------------------------
// Kernel 5 (v/col step)
__global__ __launch_bounds__(256) void v_kernel(
    const _Float16* __restrict__ Sh, const float* __restrict__ U,
    float* __restrict__ V, float* __restrict__ W,
    float f, int last, float* __restrict__ outPart) {
  __shared__ float Ul[NS];
  __shared__ float partC[16][128];
  __shared__ float partD[16][128];
  __shared__ float red[128];
  int blk = blockIdx.x;
  int bs = blk & 7, rest = blk >> 3;
  int q = rest & 3, bq = rest >> 2;
  int b = bq * 8 + bs;
  int t = threadIdx.x;
  Ul[t] = U[b * NS + t];
  Ul[t + 256] = U[b * NS + t + 256];
  __syncthreads();

  int r = t >> 4, cg = t & 15;
  const _Float16* Sb = Sh + (size_t)b * NS * NS + q * 128 + cg * 8;
  float c[8] = {}, d[8] = {};
  if (!last) {
#pragma unroll 4
    for (int s = 0; s < 32; ++s) {
      int m = s * 16 + r;
      half8 hv = *(const half8*)(Sb + (size_t)m * NS);
      float um = Ul[m];
#pragma unroll
      for (int e = 0; e < 8; ++e) c[e] += __expf(fmaf(f, (float)hv[e], um));
    }
  } else {
#pragma unroll 2
    for (int s = 0; s < 32; ++s) {
      int m = s * 16 + r;
      half8 hv = *(const half8*)(Sb + (size_t)m * NS);
      float um = Ul[m];
#pragma unroll
      for (int e = 0; e < 8; ++e) {
        float sv = (float)hv[e];
        float ev = __expf(fmaf(f, sv, um));
        c[e] += ev;
        d[e] = fmaf(sv, ev, d[e]);
      }
    }
  }
  *(f32x4*)&partC[r][cg * 8 + 0] = f32x4{c[0], c[1], c[2], c[3]};
  *(f32x4*)&partC[r][cg * 8 + 4] = f32x4{c[4], c[5], c[6], c[7]};
  if (last) {
    *(f32x4*)&partD[r][cg * 8 + 0] = f32x4{d[0], d[1], d[2], d[3]};
    *(f32x4*)&partD[r][cg * 8 + 4] = f32x4{d[4], d[5], d[6], d[7]};
  }
  __syncthreads();
  if (t < 128) {
    float ct = 0.f;
#pragma unroll
    for (int r2 = 0; r2 < 16; ++r2) ct += partC[r2][t];
    float vnew = LOG_INV_NS - __logf(ct);
    int n = b * NS + q * 128 + t;
    float vold = V[n];
    V[n] = vnew;
    W[n] = 2.f * vnew - vold;
    if (last) {
      float dt = 0.f;
#pragma unroll
      for (int r2 = 0; r2 < 16; ++r2) dt += partD[r2][t];
      red[t] = dt / ct;
    }
  }
  if (last) {
    __syncthreads();
    for (int s2 = 64; s2 > 0; s2 >>= 1) {
      if (t < s2) red[t] += red[t + s2];
      __syncthreads();
    }
    if (t == 0) outPart[b * 4 + q] = red[0] * (1.0f / (float)NS);
  }
}

// ---------------------------------------------------------------------------
// Kernel 6: combine 4 partials per batch (deterministic)
__global__ void combine_kernel(const float* __restrict__ outPart, float* __restrict__ out) {
  int b = threadIdx.x;  // 64 threads
  out[b] = outPart[4 * b] + outPart[4 * b + 1] + outPart[4 * b + 2] + outPart[4 * b + 3];
}

// ---------------------------------------------------------------------------
extern "C" void kernel_launch(void* const* d_in, const int* in_sizes, int n_in,
                              void* d_out, int out_size, void* d_ws, size_t ws_size,
                              hipStream_t stream) {
  (void)in_sizes; (void)n_in; (void)out_size; (void)ws_size;
  const float* x = (const float*)d_in[0];
  const float* y = (const float*)d_in[1];
  float* out = (float*)d_out;

  char* ws = (char*)d_ws;
  _Float16* Sh = (_Float16*)ws;                                // 32 MiB
  float* fregion = (float*)(ws + (size_t)NB * NS * NS * 2);
  float* U = fregion;                                          // 32768
  float* V = U + NB * NS;
  float* W = V + NB * NS;
  float* outPart = W + NB * NS;                                // 256

  gemm_fused<<<256, 512, 0, stream>>>(x, y, Sh);
  init_kernel<<<(NB * NS) / 256, 256, 0, stream>>>(V, W);

  for (int t = 1; t <= NITERS; ++t) {
    float f = 10.0f * (float)t;
    u_kernel<<<2048, 256, 0, stream>>>(Sh, W, U, f);
    v_kernel<<<256, 256, 0, stream>>>(Sh, U, V, W, f, t == NITERS ? 1 : 0, outPart);
  }
  combine_kernel<<<1, 64, 0, stream>>>(outPart, out);
}